// Round 1
// baseline (411.181 us; speedup 1.0000x reference)
//
#include <hip/hip_runtime.h>
#include <math.h>
#include <limits.h>

#define BB 16
#define SS 4096
#define HH 1024
#define PAD_ID 0

// Kernel A: per-batch index logic.
// start_ind = first i with mask!=0 (else 0)
// c_ind     = first i>=start with chosen_ids==PAD (else S)
// r_div     = first i>=start with rejected_ids==PAD (else S)
// has_div   = any(chosen != rejected)
// r_ind     = has_div ? r_div : c_ind          (min(c_ind,S)==c_ind)
// last      = min(c_ind, r_ind) - 1            (wrap -1 -> S-1, JAX/np semantics)
__global__ __launch_bounds__(256) void find_last_kernel(
    const int* __restrict__ chosen_ids,
    const int* __restrict__ chosen_mask,
    const int* __restrict__ rejected_ids,
    int* __restrict__ last_out,
    float* __restrict__ out)
{
    const int b = blockIdx.x;
    const int t = threadIdx.x;
    const int* cid = chosen_ids   + (size_t)b * SS;
    const int* msk = chosen_mask  + (size_t)b * SS;
    const int* rid = rejected_ids + (size_t)b * SS;

    __shared__ int s1[256];
    __shared__ int s2[256];
    __shared__ int s3[256];
    __shared__ int s_start;

    // ---- pass 1: start_ind ----
    int mymin = INT_MAX;
    for (int i = t; i < SS; i += 256) {
        if (msk[i] != 0) { mymin = i; break; }  // strided indices increase -> first hit is min
    }
    s1[t] = mymin;
    __syncthreads();
    for (int ofs = 128; ofs > 0; ofs >>= 1) {
        if (t < ofs) s1[t] = min(s1[t], s1[t + ofs]);
        __syncthreads();
    }
    if (t == 0) s_start = (s1[0] == INT_MAX) ? 0 : s1[0];
    __syncthreads();
    const int start = s_start;
    __syncthreads();  // s1 reused below

    // ---- pass 2: first-pad indices + any-divergence ----
    int cmin = INT_MAX, rmin = INT_MAX, diff = 0;
    for (int i = t; i < SS; i += 256) {
        int c = cid[i];
        int r = rid[i];
        diff |= (c != r);
        if (i >= start) {
            if (c == PAD_ID && i < cmin) cmin = i;
            if (r == PAD_ID && i < rmin) rmin = i;
        }
    }
    s1[t] = cmin; s2[t] = rmin; s3[t] = diff;
    __syncthreads();
    for (int ofs = 128; ofs > 0; ofs >>= 1) {
        if (t < ofs) {
            s1[t] = min(s1[t], s1[t + ofs]);
            s2[t] = min(s2[t], s2[t + ofs]);
            s3[t] |= s3[t + ofs];
        }
        __syncthreads();
    }
    if (t == 0) {
        int c_ind = (s1[0] == INT_MAX) ? SS : s1[0];
        int r_div = (s2[0] == INT_MAX) ? SS : s2[0];
        int r_ind = s3[0] ? r_div : c_ind;
        int last  = min(c_ind, r_ind) - 1;
        if (last < 0) last += SS;    // JAX/np negative-index wrap
        last_out[b] = last;
        if (b == 0) out[0] = 0.0f;   // zero loss accumulator inside the graph
    }
}

// Kernel B: gather the single needed row of each hidden tensor, dot with w,
// write scores, accumulate mean softplus(r-c) into out[0].
__global__ __launch_bounds__(256) void score_kernel(
    const float* __restrict__ chosen_hidden,
    const float* __restrict__ rejected_hidden,
    const float* __restrict__ w,
    const int* __restrict__ last_in,
    float* __restrict__ out)
{
    const int b = blockIdx.x;
    const int t = threadIdx.x;
    const int last = last_in[b];

    const float4* ch = (const float4*)(chosen_hidden   + ((size_t)b * SS + last) * HH);
    const float4* rh = (const float4*)(rejected_hidden + ((size_t)b * SS + last) * HH);
    const float4* wv = (const float4*)w;

    // 256 threads x float4 == 1024 == HH exactly
    float4 c4 = ch[t];
    float4 r4 = rh[t];
    float4 w4 = wv[t];
    float cs = c4.x * w4.x + c4.y * w4.y + c4.z * w4.z + c4.w * w4.w;
    float rs = r4.x * w4.x + r4.y * w4.y + r4.z * w4.z + r4.w * w4.w;

    __shared__ float sc[256];
    __shared__ float sr[256];
    sc[t] = cs; sr[t] = rs;
    __syncthreads();
    for (int ofs = 128; ofs > 0; ofs >>= 1) {
        if (t < ofs) { sc[t] += sc[t + ofs]; sr[t] += sr[t + ofs]; }
        __syncthreads();
    }
    if (t == 0) {
        float c = sc[0];
        float r = sr[0];
        out[1 + b]      = c;   // chosen_mean_scores
        out[1 + BB + b] = r;   // rejected_mean_scores
        // -log_sigmoid(c - r) = softplus(r - c), numerically stable form
        float x  = r - c;
        float sp = fmaxf(x, 0.0f) + log1pf(expf(-fabsf(x)));
        atomicAdd(out, sp * (1.0f / BB));
    }
}

extern "C" void kernel_launch(void* const* d_in, const int* in_sizes, int n_in,
                              void* d_out, int out_size, void* d_ws, size_t ws_size,
                              hipStream_t stream) {
    const int*   chosen_ids      = (const int*)d_in[0];
    const int*   chosen_mask     = (const int*)d_in[1];
    const int*   rejected_ids    = (const int*)d_in[2];
    const float* chosen_hidden   = (const float*)d_in[3];
    const float* rejected_hidden = (const float*)d_in[4];
    const float* v_head_w        = (const float*)d_in[5];
    float* out = (float*)d_out;
    int*   last_ws = (int*)d_ws;

    find_last_kernel<<<BB, 256, 0, stream>>>(chosen_ids, chosen_mask, rejected_ids,
                                             last_ws, out);
    score_kernel<<<BB, 256, 0, stream>>>(chosen_hidden, rejected_hidden, v_head_w,
                                         last_ws, out);
}